// Round 4
// baseline (183.222 us; speedup 1.0000x reference)
//
#include <hip/hip_runtime.h>
#include <math.h>

// Problem constants: B=2, L=768, H=256, NH=8, HD=32
#define NL 768
#define NHID 256
#define NBLK 256

typedef __attribute__((ext_vector_type(8))) short bf16x8;  // 8 bf16 = 4 VGPR
typedef __attribute__((ext_vector_type(4))) float f32x4;
typedef _Float16 h2v __attribute__((ext_vector_type(2)));

static __device__ __forceinline__ ushort f2bf(float f) {
    uint u = __float_as_uint(f);
    u += 0x7fffu + ((u >> 16) & 1u);           // round-to-nearest-even
    return (ushort)(u >> 16);
}
static __device__ __forceinline__ uint pack2(float a, float b) {
    return (uint)f2bf(a) | ((uint)f2bf(b) << 16);
}
static __device__ __forceinline__ uint4 pack8(float4 a, float4 b) {
    uint4 r;
    r.x = pack2(a.x, a.y); r.y = pack2(a.z, a.w);
    r.z = pack2(b.x, b.y); r.w = pack2(b.z, b.w);
    return r;
}
// packed fp16: relu(a+b) via v_pk_add_f16 + v_pk_max_f16
static __device__ __forceinline__ uint addrelu2(uint a, uint b) {
    h2v s = __builtin_bit_cast(h2v, a) + __builtin_bit_cast(h2v, b);
    h2v z = {(_Float16)0.f, (_Float16)0.f};
    s = __builtin_elementwise_max(s, z);
    return __builtin_bit_cast(uint, s);
}
// fp32 += dot2(fp16x2, fp16x2) via v_dot2_f32_f16
static __device__ __forceinline__ float fdot2u(uint a, uint b, float c) {
#if __has_builtin(__builtin_amdgcn_fdot2)
    return __builtin_amdgcn_fdot2(__builtin_bit_cast(h2v, a),
                                  __builtin_bit_cast(h2v, b), c, false);
#else
    h2v x = __builtin_bit_cast(h2v, a), y = __builtin_bit_cast(h2v, b);
    return fmaf((float)x[1], (float)y[1], fmaf((float)x[0], (float)y[0], c));
#endif
}

// ---------------------------------------------------------------------------
// Grid barrier: all NBLK blocks co-resident (256 blocks <= 256 CUs, 35KB LDS).
// Counter zeroed by hipMemsetAsync at each kernel_launch.
// ---------------------------------------------------------------------------
static __device__ __forceinline__ void grid_bar(uint* cnt, uint target) {
    __syncthreads();
    if (threadIdx.x == 0) {
        __threadfence();
        __hip_atomic_fetch_add(cnt, 1u, __ATOMIC_RELEASE, __HIP_MEMORY_SCOPE_AGENT);
        while (__hip_atomic_load(cnt, __ATOMIC_ACQUIRE, __HIP_MEMORY_SCOPE_AGENT) < target)
            __builtin_amdgcn_s_sleep(1);
        __threadfence();
    }
    __syncthreads();
}

// ---------------------------------------------------------------------------
// MFMA GEMM tile (64 x BN), BK=32: C = A[m,k] * Bt[n,k] + bias[n]
// ---------------------------------------------------------------------------
template<bool A_BF16, bool B_BF16, bool OUT_HALF, bool OUT_BF16, int BN>
static __device__ void gemm_tile(
    const void* __restrict__ Ap, int lda, const void* __restrict__ Bp, int ldb,
    const float* __restrict__ bias, void* __restrict__ Cp, int ldc, int K,
    int m0, int n0, char* smem)
{
    ushort* As = (ushort*)smem;                 // [64*40]
    ushort* Bs = (ushort*)(smem + 64 * 40 * 2); // [BN*40]
    constexpr int COLF = BN / 32;
    const int t = threadIdx.x;
    const int lane = t & 63, w = t >> 6;
    const int lg = lane >> 4, lc = lane & 15;
    const int wr = (w >> 1) * 32, wc = (w & 1) * (BN / 2);
    const int sr = t >> 2, sc = (t & 3) * 8;
    f32x4 acc[2][COLF] = {};
    for (int k0 = 0; k0 < K; k0 += 32) {
        __syncthreads();
        if (A_BF16) {
            *(uint4*)&As[sr * 40 + sc] =
                *(const uint4*)((const ushort*)Ap + (size_t)(m0 + sr) * lda + k0 + sc);
        } else {
            const float* ap = (const float*)Ap + (size_t)(m0 + sr) * lda + k0 + sc;
            *(uint4*)&As[sr * 40 + sc] = pack8(*(const float4*)ap, *(const float4*)(ap + 4));
        }
        #pragma unroll
        for (int r0 = 0; r0 < BN; r0 += 64) {
            if (B_BF16) {
                *(uint4*)&Bs[(r0 + sr) * 40 + sc] =
                    *(const uint4*)((const ushort*)Bp + (size_t)(n0 + r0 + sr) * ldb + k0 + sc);
            } else {
                const float* bp = (const float*)Bp + (size_t)(n0 + r0 + sr) * ldb + k0 + sc;
                *(uint4*)&Bs[(r0 + sr) * 40 + sc] = pack8(*(const float4*)bp, *(const float4*)(bp + 4));
            }
        }
        __syncthreads();
        bf16x8 a0 = *(const bf16x8*)&As[(wr + lc) * 40 + 8 * lg];
        bf16x8 a1 = *(const bf16x8*)&As[(wr + 16 + lc) * 40 + 8 * lg];
        #pragma unroll
        for (int j = 0; j < COLF; ++j) {
            bf16x8 bj = *(const bf16x8*)&Bs[(wc + 16 * j + lc) * 40 + 8 * lg];
            acc[0][j] = __builtin_amdgcn_mfma_f32_16x16x32_bf16(a0, bj, acc[0][j], 0, 0, 0);
            acc[1][j] = __builtin_amdgcn_mfma_f32_16x16x32_bf16(a1, bj, acc[1][j], 0, 0, 0);
        }
    }
    #pragma unroll
    for (int j = 0; j < COLF; ++j) {
        int n = n0 + wc + 16 * j + lc;
        float bv = bias[n];
        #pragma unroll
        for (int i = 0; i < 2; ++i) {
            #pragma unroll
            for (int ii = 0; ii < 4; ++ii) {
                int m = m0 + wr + 16 * i + 4 * lg + ii;
                float v = acc[i][j][ii] + bv;
                if (OUT_BF16)      ((ushort*)Cp)[(size_t)m * ldc + n] = f2bf(v);
                else if (OUT_HALF) ((_Float16*)Cp)[(size_t)m * ldc + n] = (_Float16)v;
                else               ((float*)Cp)[(size_t)m * ldc + n] = v;
            }
        }
    }
}

// ---------------------------------------------------------------------------
// Flash-attention tile: 64 q-rows of one (b,h); 4 waves x 16 rows.
// ---------------------------------------------------------------------------
static __device__ void attn_tile(
    const ushort* __restrict__ qkv, ushort* __restrict__ attnb,
    int m0, int bh, char* smem)
{
    ushort* Qs = (ushort*)smem;                  // 64*40
    ushort* Ks = Qs + 64 * 40;                   // 64*40
    ushort* Vt = Ks + 64 * 40;                   // 32*72
    ushort* Ps = Vt + 32 * 72;                   // 4*16*72
    const int b = bh >> 3, h = bh & 7;
    const int t = threadIdx.x, lane = t & 63, w = t >> 6;
    const int lg = lane >> 4, lc = lane & 15;
    const int sr = t >> 2, sc = (t & 3) * 8;
    ushort* Pw = Ps + w * (16 * 72);
    const float SC = 0.17677669529663687f;   // 1/sqrt(32)

    *(uint4*)&Qs[sr * 40 + sc] =
        *(const uint4*)(qkv + (size_t)(b * NL + m0 + sr) * 768 + h * 32 + sc);

    f32x4 o0 = {}, o1 = {};
    float mr[4] = {-1e30f, -1e30f, -1e30f, -1e30f};
    float lr[4] = {0.f, 0.f, 0.f, 0.f};
    bf16x8 qa;

    for (int k0 = 0; k0 < NL; k0 += 64) {
        __syncthreads();
        *(uint4*)&Ks[sr * 40 + sc] =
            *(const uint4*)(qkv + (size_t)(b * NL + k0 + sr) * 768 + 256 + h * 32 + sc);
        {   // V staged transposed: Vt[d][k]
            uint4 vv = *(const uint4*)(qkv + (size_t)(b * NL + k0 + sr) * 768 + 512 + h * 32 + sc);
            uint vw[4] = {vv.x, vv.y, vv.z, vv.w};
            #pragma unroll
            for (int j = 0; j < 8; ++j)
                Vt[(sc + j) * 72 + sr] = (ushort)((vw[j >> 1] >> ((j & 1) * 16)) & 0xffffu);
        }
        __syncthreads();
        if (k0 == 0) qa = *(const bf16x8*)&Qs[(16 * w + lc) * 40 + 8 * lg];

        f32x4 s[4];
        #pragma unroll
        for (int t4 = 0; t4 < 4; ++t4) {
            bf16x8 kb = *(const bf16x8*)&Ks[(16 * t4 + lc) * 40 + 8 * lg];
            f32x4 z = {};
            s[t4] = __builtin_amdgcn_mfma_f32_16x16x32_bf16(qa, kb, z, 0, 0, 0);
        }
        #pragma unroll
        for (int i = 0; i < 4; ++i) {
            float mx = fmaxf(fmaxf(s[0][i], s[1][i]), fmaxf(s[2][i], s[3][i]));
            #pragma unroll
            for (int off = 1; off < 16; off <<= 1) mx = fmaxf(mx, __shfl_xor(mx, off));
            float mnew = fmaxf(mr[i], mx * SC);
            float resc = __expf(mr[i] - mnew);
            float tsum = 0.f;
            #pragma unroll
            for (int t4 = 0; t4 < 4; ++t4) {
                float p = __expf(s[t4][i] * SC - mnew);
                tsum += p;
                Pw[(4 * lg + i) * 72 + 16 * t4 + lc] = f2bf(p);
            }
            #pragma unroll
            for (int off = 1; off < 16; off <<= 1) tsum += __shfl_xor(tsum, off);
            mr[i] = mnew;
            lr[i] = lr[i] * resc + tsum;
            o0[i] *= resc;
            o1[i] *= resc;
        }
        bf16x8 pa0 = *(const bf16x8*)&Pw[lc * 72 + 8 * lg];
        bf16x8 pa1 = *(const bf16x8*)&Pw[lc * 72 + 32 + 8 * lg];
        bf16x8 v00 = *(const bf16x8*)&Vt[lc * 72 + 8 * lg];
        bf16x8 v10 = *(const bf16x8*)&Vt[lc * 72 + 32 + 8 * lg];
        bf16x8 v01 = *(const bf16x8*)&Vt[(16 + lc) * 72 + 8 * lg];
        bf16x8 v11 = *(const bf16x8*)&Vt[(16 + lc) * 72 + 32 + 8 * lg];
        o0 = __builtin_amdgcn_mfma_f32_16x16x32_bf16(pa0, v00, o0, 0, 0, 0);
        o0 = __builtin_amdgcn_mfma_f32_16x16x32_bf16(pa1, v10, o0, 0, 0, 0);
        o1 = __builtin_amdgcn_mfma_f32_16x16x32_bf16(pa0, v01, o1, 0, 0, 0);
        o1 = __builtin_amdgcn_mfma_f32_16x16x32_bf16(pa1, v11, o1, 0, 0, 0);
    }
    #pragma unroll
    for (int i = 0; i < 4; ++i) {
        float inv = 1.f / lr[i];
        size_t row = (size_t)(b * NL + m0 + 16 * w + 4 * lg + i);
        attnb[row * 256 + h * 32 + lc]      = f2bf(o0[i] * inv);
        attnb[row * 256 + h * 32 + 16 + lc] = f2bf(o1[i] * inv);
    }
}

// ---------------------------------------------------------------------------
// Weight-combine tile: WcT[c',k] = sum_j out_w[j,k] * w1x[j, c'&127]
// ---------------------------------------------------------------------------
static __device__ void combine_w_tile(
    const float* __restrict__ out_w, const float* __restrict__ w1,
    ushort* __restrict__ WcT, int k0, int c0, char* smem)
{
    float (*Aw)[33] = (float(*)[33])smem;
    float (*Bw)[33] = (float(*)[33])(smem + 32 * 33 * 4);
    const float* w1x = w1 + (c0 >= 128 ? 256 * 128 : 0);
    const int cc0 = c0 & 127;
    const int t = threadIdx.x;
    const int tx = t & 15, ty = t >> 4;
    float acc[2][2] = {};
    for (int j0 = 0; j0 < 256; j0 += 32) {
        __syncthreads();
        for (int u = t; u < 32 * 32; u += 256) {
            int r = u >> 5, c = u & 31;
            Aw[r][c] = out_w[(size_t)(j0 + r) * 256 + k0 + c];
            Bw[r][c] = w1x[(size_t)(j0 + r) * 128 + cc0 + c];
        }
        __syncthreads();
        #pragma unroll
        for (int jj = 0; jj < 32; ++jj) {
            float a0 = Aw[jj][ty * 2], a1 = Aw[jj][ty * 2 + 1];
            float b0 = Bw[jj][tx * 2], b1v = Bw[jj][tx * 2 + 1];
            acc[0][0] = fmaf(a0, b0, acc[0][0]);
            acc[0][1] = fmaf(a0, b1v, acc[0][1]);
            acc[1][0] = fmaf(a1, b0, acc[1][0]);
            acc[1][1] = fmaf(a1, b1v, acc[1][1]);
        }
    }
    #pragma unroll
    for (int i = 0; i < 2; ++i)
        #pragma unroll
        for (int j = 0; j < 2; ++j)
            WcT[(size_t)(c0 + tx * 2 + j) * 256 + (k0 + ty * 2 + i)] = f2bf(acc[i][j]);
}

// bc[c'] = out_b . w1col(c')  (+ b1 for the row half)
static __device__ void combine_bias_unit(
    const float* __restrict__ out_b, const float* __restrict__ w1,
    const float* __restrict__ b1, float* __restrict__ bc)
{
    const int t = threadIdx.x;
    const float* w1x = w1 + (t >= 128 ? 256 * 128 : 0);
    const int cc = t & 127;
    float a = 0.f;
    #pragma unroll 8
    for (int j = 0; j < 256; ++j)
        a = fmaf(out_b[j], w1x[(size_t)j * 128 + cc], a);
    bc[t] = a + (t < 128 ? b1[cc] : 0.f);
}

// ---------------------------------------------------------------------------
// Pairwise tile 64x64 (fp16 dot2): out[b,i,j] = sum_c relu(r+c)*w2 + b2
// ---------------------------------------------------------------------------
static __device__ void pairwise_tile(
    const ushort* __restrict__ rowcol, const float* __restrict__ w2,
    const float* __restrict__ b2, float* __restrict__ out,
    int b, int i0, int j0, char* smem)
{
    ushort* rs = (ushort*)smem;        // [64*136] fp16
    ushort* cs = rs + 64 * 136;        // [64*136] fp16
    uint* w2u = (uint*)(cs + 64 * 136); // 64 x half2
    const int t = threadIdx.x;
    __syncthreads();   // LDS reuse guard (2nd unit / phase entry)
    const int sr = t >> 2, c32 = (t & 3) * 32;
    {
        const ushort* rp = rowcol + (size_t)(b * NL + i0 + sr) * 256 + c32;
        const ushort* cp = rowcol + (size_t)(b * NL + j0 + sr) * 256 + 128 + c32;
        #pragma unroll
        for (int q = 0; q < 4; ++q) {
            *(uint4*)&rs[sr * 136 + c32 + q * 8] = *(const uint4*)(rp + q * 8);
            *(uint4*)&cs[sr * 136 + c32 + q * 8] = *(const uint4*)(cp + q * 8);
        }
    }
    if (t < 64) {
        float2 wv = *(const float2*)&w2[2 * t];
        h2v hw = {(_Float16)wv.x, (_Float16)wv.y};
        w2u[t] = __builtin_bit_cast(uint, hw);
    }
    __syncthreads();
    const int lane = t & 63, w = t >> 6;
    const int rg = lane >> 3, cg = lane & 7;
    const int wr = (w >> 1) * 32, wc = (w & 1) * 32;
    float acc[4][4] = {};
    for (int c8 = 0; c8 < 128; c8 += 8) {
        uint wu[4];
        *(uint4*)wu = *(const uint4*)&w2u[c8 >> 1];
        uint ru[4][4], cu[4][4];
        #pragma unroll
        for (int i = 0; i < 4; ++i) {
            uint4 u = *(const uint4*)&rs[(wr + rg + 8 * i) * 136 + c8];
            ru[i][0] = u.x; ru[i][1] = u.y; ru[i][2] = u.z; ru[i][3] = u.w;
            uint4 v = *(const uint4*)&cs[(wc + cg + 8 * i) * 136 + c8];
            cu[i][0] = v.x; cu[i][1] = v.y; cu[i][2] = v.z; cu[i][3] = v.w;
        }
        #pragma unroll
        for (int i = 0; i < 4; ++i)
            #pragma unroll
            for (int j = 0; j < 4; ++j) {
                float a = acc[i][j];
                #pragma unroll
                for (int p = 0; p < 4; ++p)
                    a = fdot2u(addrelu2(ru[i][p], cu[j][p]), wu[p], a);
                acc[i][j] = a;
            }
    }
    const float bb = b2[0];
    #pragma unroll
    for (int i = 0; i < 4; ++i)
        #pragma unroll
        for (int j = 0; j < 4; ++j)
            out[(size_t)(b * NL + i0 + wr + rg + 8 * i) * NL + j0 + wc + cg + 8 * j] =
                acc[i][j] + bb;
}

// ---------------------------------------------------------------------------
// The single persistent kernel: 4 phases over 256 blocks.
// ---------------------------------------------------------------------------
__global__ __launch_bounds__(256) void fused_all(
    const float* __restrict__ features, const float* __restrict__ in_proj_w,
    const float* __restrict__ in_proj_b, const float* __restrict__ out_w,
    const float* __restrict__ out_b, const float* __restrict__ w1,
    const float* __restrict__ b1, const float* __restrict__ w2,
    const float* __restrict__ b2,
    ushort* __restrict__ qkvb, ushort* __restrict__ attnb,
    ushort* __restrict__ WcT, float* __restrict__ bc,
    ushort* __restrict__ rowcol, float* __restrict__ out, uint* cnt)
{
    __shared__ __align__(16) char smem[35072];
    const int wg = blockIdx.x;

    // Phase 0: qkv GEMM (144 tiles 64x128) + combine_w (64) + combine_bias (1)
    for (int u = wg; u < 209; u += NBLK) {
        if (u < 144)
            gemm_tile<false, false, false, true, 128>(
                features, 256, in_proj_w, 256, in_proj_b, qkvb, 768, 256,
                (u / 6) * 64, (u % 6) * 128, smem);
        else if (u < 208)
            combine_w_tile(out_w, w1, WcT, ((u - 144) & 7) * 32, ((u - 144) >> 3) * 32, smem);
        else
            combine_bias_unit(out_b, w1, b1, bc);
    }
    grid_bar(cnt, NBLK);

    // Phase 1: flash attention (192 tiles: 12 m x 16 bh)
    for (int u = wg; u < 192; u += NBLK)
        attn_tile(qkvb, attnb, (u % 12) * 64, u / 12, smem);
    grid_bar(cnt, 2 * NBLK);

    // Phase 2: rowcol = attn @ WcT + bc -> fp16 (96 tiles 64x64)
    for (int u = wg; u < 96; u += NBLK)
        gemm_tile<true, true, true, false, 64>(
            attnb, 256, WcT, 256, bc, rowcol, 256, 256,
            (u / 4) * 64, (u % 4) * 64, smem);
    grid_bar(cnt, 3 * NBLK);

    // Phase 3: pairwise contact MLP (288 tiles 64x64)
    for (int u = wg; u < 288; u += NBLK) {
        int r = u % 144;
        pairwise_tile(rowcol, w2, b2, out, u / 144, (r / 12) * 64, (r % 12) * 64, smem);
    }
}

// ---------------------------------------------------------------------------
extern "C" void kernel_launch(void* const* d_in, const int* in_sizes, int n_in,
                              void* d_out, int out_size, void* d_ws, size_t ws_size,
                              hipStream_t stream)
{
    const float* features  = (const float*)d_in[0];  // [2,768,256]
    const float* in_proj_w = (const float*)d_in[1];  // [768,256]
    const float* in_proj_b = (const float*)d_in[2];  // [768]
    const float* out_w     = (const float*)d_in[3];  // [256,256]
    const float* out_b     = (const float*)d_in[4];  // [256]
    const float* w1        = (const float*)d_in[5];  // [512,128]
    const float* b1        = (const float*)d_in[6];  // [128]
    const float* w2        = (const float*)d_in[7];  // [128,1]
    const float* b2        = (const float*)d_in[8];  // [1]
    float* out = (float*)d_out;                      // [2,768,768]

    uint*   cnt    = (uint*)d_ws;                    // 16 B (barrier counter)
    ushort* qkvb   = (ushort*)((char*)d_ws + 16);    // [1536,768] bf16
    ushort* attnb  = qkvb + 1179648;                 // [1536,256] bf16
    ushort* WcT    = attnb + 393216;                 // [256,256]  bf16
    float*  bc     = (float*)(WcT + 65536);          // [256] fp32
    ushort* rowcol = (ushort*)(bc + 256);            // [1536,256] fp16

    hipMemsetAsync(cnt, 0, 16, stream);
    fused_all<<<NBLK, 256, 0, stream>>>(
        features, in_proj_w, in_proj_b, out_w, out_b, w1, b1, w2, b2,
        qkvb, attnb, WcT, bc, rowcol, out, cnt);
}

// Round 5
// 64.496 us; speedup vs baseline: 2.8408x; 2.8408x over previous
//
#include <hip/hip_runtime.h>
#include <math.h>

// Problem constants: B=2, L=768, H=256, NH=8, HD=32
#define NL 768
#define NHID 256

typedef __attribute__((ext_vector_type(8))) short bf16x8;  // 8 bf16 = 4 VGPR
typedef __attribute__((ext_vector_type(4))) float f32x4;
typedef _Float16 h2v __attribute__((ext_vector_type(2)));

static __device__ __forceinline__ ushort f2bf(float f) {
    uint u = __float_as_uint(f);
    u += 0x7fffu + ((u >> 16) & 1u);           // round-to-nearest-even
    return (ushort)(u >> 16);
}
static __device__ __forceinline__ uint pack2(float a, float b) {
    return (uint)f2bf(a) | ((uint)f2bf(b) << 16);
}
static __device__ __forceinline__ uint4 pack8(float4 a, float4 b) {
    uint4 r;
    r.x = pack2(a.x, a.y); r.y = pack2(a.z, a.w);
    r.z = pack2(b.x, b.y); r.w = pack2(b.z, b.w);
    return r;
}
// packed fp16: relu(a+b) via v_pk_add_f16 + v_pk_max_f16
static __device__ __forceinline__ uint addrelu2(uint a, uint b) {
    h2v s = __builtin_bit_cast(h2v, a) + __builtin_bit_cast(h2v, b);
    h2v z = {(_Float16)0.f, (_Float16)0.f};
    s = __builtin_elementwise_max(s, z);
    return __builtin_bit_cast(uint, s);
}
// fp32 += dot2(fp16x2, fp16x2) via v_dot2_f32_f16
static __device__ __forceinline__ float fdot2u(uint a, uint b, float c) {
#if __has_builtin(__builtin_amdgcn_fdot2)
    return __builtin_amdgcn_fdot2(__builtin_bit_cast(h2v, a),
                                  __builtin_bit_cast(h2v, b), c, false);
#else
    h2v x = __builtin_bit_cast(h2v, a), y = __builtin_bit_cast(h2v, b);
    return fmaf((float)x[1], (float)y[1], fmaf((float)x[0], (float)y[0], c));
#endif
}

// ---------------------------------------------------------------------------
// Front kernel: role by blockIdx.x.
//  [0,576):   qkv 32x64 tile:  qkv[m,n] = features[m,:]·in_proj_w[n,:] + b
//  [576,640): combine_w 32x32: WcT[c',k] = sum_j out_w[j,k]*w1x[j,c'&127]
//  640:       combine_bias
// ---------------------------------------------------------------------------
__global__ __launch_bounds__(256) void front_kernel(
    const float* __restrict__ features, const float* __restrict__ in_proj_w,
    const float* __restrict__ in_proj_b, const float* __restrict__ out_w,
    const float* __restrict__ out_b, const float* __restrict__ w1,
    const float* __restrict__ b1,
    ushort* __restrict__ qkvb, ushort* __restrict__ WcT, float* __restrict__ bc)
{
    const int u = blockIdx.x;
    const int t = threadIdx.x;
    if (u < 576) {
        __shared__ __align__(16) ushort As[32 * 40];
        __shared__ __align__(16) ushort Bs[64 * 40];
        const int m0 = (u / 12) * 32, n0 = (u % 12) * 64;
        const int lane = t & 63, w = t >> 6;
        const int lg = lane >> 4, lc = lane & 15;
        const int wr = (w >> 1) * 16, wc = (w & 1) * 32;
        const int sr = t >> 2, sc = (t & 3) * 8;   // sr 0..63
        f32x4 acc[2] = {};
        for (int k0 = 0; k0 < 256; k0 += 32) {
            __syncthreads();
            if (t < 128) {
                const float* ap = features + (size_t)(m0 + sr) * 256 + k0 + sc;
                *(uint4*)&As[sr * 40 + sc] = pack8(*(const float4*)ap, *(const float4*)(ap + 4));
            }
            const float* bp = in_proj_w + (size_t)(n0 + sr) * 256 + k0 + sc;
            *(uint4*)&Bs[sr * 40 + sc] = pack8(*(const float4*)bp, *(const float4*)(bp + 4));
            __syncthreads();
            bf16x8 a = *(const bf16x8*)&As[(wr + lc) * 40 + 8 * lg];
            #pragma unroll
            for (int j = 0; j < 2; ++j) {
                bf16x8 bj = *(const bf16x8*)&Bs[(wc + 16 * j + lc) * 40 + 8 * lg];
                acc[j] = __builtin_amdgcn_mfma_f32_16x16x32_bf16(a, bj, acc[j], 0, 0, 0);
            }
        }
        #pragma unroll
        for (int j = 0; j < 2; ++j) {
            int n = n0 + wc + 16 * j + lc;
            float bv = in_proj_b[n];
            #pragma unroll
            for (int ii = 0; ii < 4; ++ii) {
                int m = m0 + wr + 4 * lg + ii;
                qkvb[(size_t)m * 768 + n] = f2bf(acc[j][ii] + bv);
            }
        }
    } else if (u < 640) {
        __shared__ float Aw[32][33];
        __shared__ float Bw[32][33];
        const int u2 = u - 576;
        const int k0 = (u2 & 7) * 32, c0 = (u2 >> 3) * 32;
        const float* w1x = w1 + (c0 >= 128 ? 256 * 128 : 0);
        const int cc0 = c0 & 127;
        const int tx = t & 15, ty = t >> 4;
        float acc[2][2] = {};
        for (int j0 = 0; j0 < 256; j0 += 32) {
            __syncthreads();
            for (int v = t; v < 32 * 32; v += 256) {
                int r = v >> 5, c = v & 31;
                Aw[r][c] = out_w[(size_t)(j0 + r) * 256 + k0 + c];
                Bw[r][c] = w1x[(size_t)(j0 + r) * 128 + cc0 + c];
            }
            __syncthreads();
            #pragma unroll
            for (int jj = 0; jj < 32; ++jj) {
                float a0 = Aw[jj][ty * 2], a1 = Aw[jj][ty * 2 + 1];
                float b0 = Bw[jj][tx * 2], b1v = Bw[jj][tx * 2 + 1];
                acc[0][0] = fmaf(a0, b0, acc[0][0]);
                acc[0][1] = fmaf(a0, b1v, acc[0][1]);
                acc[1][0] = fmaf(a1, b0, acc[1][0]);
                acc[1][1] = fmaf(a1, b1v, acc[1][1]);
            }
        }
        #pragma unroll
        for (int i = 0; i < 2; ++i)
            #pragma unroll
            for (int j = 0; j < 2; ++j)
                WcT[(size_t)(c0 + tx * 2 + j) * 256 + (k0 + ty * 2 + i)] = f2bf(acc[i][j]);
    } else {
        const float* w1x = w1 + (t >= 128 ? 256 * 128 : 0);
        const int cc = t & 127;
        float a = 0.f;
        #pragma unroll 8
        for (int j = 0; j < 256; ++j)
            a = fmaf(out_b[j], w1x[(size_t)j * 128 + cc], a);
        bc[t] = a + (t < 128 ? b1[cc] : 0.f);
    }
}

// ---------------------------------------------------------------------------
// Flash attention: 32 q-rows per block, 2 waves x 16 rows, 128 threads.
// grid (24, 16).  qkv bf16 [1536,768], out attn bf16 [1536,256].
// ---------------------------------------------------------------------------
__global__ __launch_bounds__(128) void attn_kernel(
    const ushort* __restrict__ qkv, ushort* __restrict__ attnb)
{
    __shared__ __align__(16) ushort Qs[32 * 40];
    __shared__ __align__(16) ushort Ks[64 * 40];
    __shared__ __align__(16) ushort Vt[32 * 72];
    __shared__ __align__(16) ushort Ps[2 * 16 * 72];
    const int bh = blockIdx.y, b = bh >> 3, h = bh & 7;
    const int m0 = blockIdx.x * 32;
    const int t = threadIdx.x, lane = t & 63, w = t >> 6;
    const int lg = lane >> 4, lc = lane & 15;
    const int sr = t >> 2, sc = (t & 3) * 8;    // sr 0..31
    ushort* Pw = Ps + w * (16 * 72);
    const float SC = 0.17677669529663687f;   // 1/sqrt(32)

    *(uint4*)&Qs[sr * 40 + sc] =
        *(const uint4*)(qkv + (size_t)(b * NL + m0 + sr) * 768 + h * 32 + sc);

    f32x4 o0 = {}, o1 = {};
    float mr[4] = {-1e30f, -1e30f, -1e30f, -1e30f};
    float lr[4] = {0.f, 0.f, 0.f, 0.f};
    bf16x8 qa;

    for (int k0 = 0; k0 < NL; k0 += 64) {
        __syncthreads();   // WAR: prev-iter reads done (iter0: Qs visible)
        *(uint4*)&Ks[sr * 40 + sc] =
            *(const uint4*)(qkv + (size_t)(b * NL + k0 + sr) * 768 + 256 + h * 32 + sc);
        *(uint4*)&Ks[(sr + 32) * 40 + sc] =
            *(const uint4*)(qkv + (size_t)(b * NL + k0 + sr + 32) * 768 + 256 + h * 32 + sc);
        #pragma unroll
        for (int half = 0; half < 2; ++half) {   // V transposed: Vt[d][k]
            int r = sr + 32 * half;
            uint4 vv = *(const uint4*)(qkv + (size_t)(b * NL + k0 + r) * 768 + 512 + h * 32 + sc);
            uint vw[4] = {vv.x, vv.y, vv.z, vv.w};
            #pragma unroll
            for (int j = 0; j < 8; ++j)
                Vt[(sc + j) * 72 + r] = (ushort)((vw[j >> 1] >> ((j & 1) * 16)) & 0xffffu);
        }
        __syncthreads();
        if (k0 == 0) qa = *(const bf16x8*)&Qs[(16 * w + lc) * 40 + 8 * lg];

        f32x4 s[4];
        #pragma unroll
        for (int t4 = 0; t4 < 4; ++t4) {
            bf16x8 kb = *(const bf16x8*)&Ks[(16 * t4 + lc) * 40 + 8 * lg];
            f32x4 z = {};
            s[t4] = __builtin_amdgcn_mfma_f32_16x16x32_bf16(qa, kb, z, 0, 0, 0);
        }
        #pragma unroll
        for (int i = 0; i < 4; ++i) {
            float mx = fmaxf(fmaxf(s[0][i], s[1][i]), fmaxf(s[2][i], s[3][i]));
            #pragma unroll
            for (int off = 1; off < 16; off <<= 1) mx = fmaxf(mx, __shfl_xor(mx, off));
            float mnew = fmaxf(mr[i], mx * SC);
            float resc = __expf(mr[i] - mnew);
            float tsum = 0.f;
            #pragma unroll
            for (int t4 = 0; t4 < 4; ++t4) {
                float p = __expf(s[t4][i] * SC - mnew);
                tsum += p;
                Pw[(4 * lg + i) * 72 + 16 * t4 + lc] = f2bf(p);
            }
            #pragma unroll
            for (int off = 1; off < 16; off <<= 1) tsum += __shfl_xor(tsum, off);
            mr[i] = mnew;
            lr[i] = lr[i] * resc + tsum;
            o0[i] *= resc;
            o1[i] *= resc;
        }
        bf16x8 pa0 = *(const bf16x8*)&Pw[lc * 72 + 8 * lg];
        bf16x8 pa1 = *(const bf16x8*)&Pw[lc * 72 + 32 + 8 * lg];
        bf16x8 v00 = *(const bf16x8*)&Vt[lc * 72 + 8 * lg];
        bf16x8 v10 = *(const bf16x8*)&Vt[lc * 72 + 32 + 8 * lg];
        bf16x8 v01 = *(const bf16x8*)&Vt[(16 + lc) * 72 + 8 * lg];
        bf16x8 v11 = *(const bf16x8*)&Vt[(16 + lc) * 72 + 32 + 8 * lg];
        o0 = __builtin_amdgcn_mfma_f32_16x16x32_bf16(pa0, v00, o0, 0, 0, 0);
        o0 = __builtin_amdgcn_mfma_f32_16x16x32_bf16(pa1, v10, o0, 0, 0, 0);
        o1 = __builtin_amdgcn_mfma_f32_16x16x32_bf16(pa0, v01, o1, 0, 0, 0);
        o1 = __builtin_amdgcn_mfma_f32_16x16x32_bf16(pa1, v11, o1, 0, 0, 0);
    }
    #pragma unroll
    for (int i = 0; i < 4; ++i) {
        float inv = 1.f / lr[i];
        size_t row = (size_t)(b * NL + m0 + 16 * w + 4 * lg + i);
        attnb[row * 256 + h * 32 + lc]      = f2bf(o0[i] * inv);
        attnb[row * 256 + h * 32 + 16 + lc] = f2bf(o1[i] * inv);
    }
}

// ---------------------------------------------------------------------------
// rowcol = attn @ Wc + bc -> fp16 [1536,256].  32x32 tiles, grid (48,8).
// ---------------------------------------------------------------------------
__global__ __launch_bounds__(256) void rowcol_kernel(
    const ushort* __restrict__ attnb, const ushort* __restrict__ WcT,
    const float* __restrict__ bc, ushort* __restrict__ rowcol)
{
    __shared__ __align__(16) ushort As[32 * 40];
    __shared__ __align__(16) ushort Bs[32 * 40];
    const int m0 = blockIdx.x * 32, n0 = blockIdx.y * 32;
    const int t = threadIdx.x, lane = t & 63, w = t >> 6;
    const int lg = lane >> 4, lc = lane & 15;
    const int wr = (w >> 1) * 16, wc = (w & 1) * 16;
    const int tt = t & 127, sr = tt >> 2, sc = (tt & 3) * 8;
    f32x4 acc = {};
    for (int k0 = 0; k0 < 256; k0 += 32) {
        __syncthreads();
        if (t < 128)
            *(uint4*)&As[sr * 40 + sc] =
                *(const uint4*)(attnb + (size_t)(m0 + sr) * 256 + k0 + sc);
        else
            *(uint4*)&Bs[sr * 40 + sc] =
                *(const uint4*)(WcT + (size_t)(n0 + sr) * 256 + k0 + sc);
        __syncthreads();
        bf16x8 a = *(const bf16x8*)&As[(wr + lc) * 40 + 8 * lg];
        bf16x8 bb = *(const bf16x8*)&Bs[(wc + lc) * 40 + 8 * lg];
        acc = __builtin_amdgcn_mfma_f32_16x16x32_bf16(a, bb, acc, 0, 0, 0);
    }
    int n = n0 + wc + lc;
    float bv = bc[n];
    #pragma unroll
    for (int ii = 0; ii < 4; ++ii) {
        int m = m0 + wr + 4 * lg + ii;
        ((_Float16*)rowcol)[(size_t)m * 256 + n] = (_Float16)(acc[ii] + bv);
    }
}

// ---------------------------------------------------------------------------
// Pairwise 64x64 (fp16 dot2): out[b,i,j] = sum_c relu(r+c)*w2 + b2
// grid (12, 12, 2).
// ---------------------------------------------------------------------------
__global__ __launch_bounds__(256) void pairwise_kernel(
    const ushort* __restrict__ rowcol, const float* __restrict__ w2,
    const float* __restrict__ b2, float* __restrict__ out)
{
    __shared__ __align__(16) ushort rs[64 * 136];
    __shared__ __align__(16) ushort cs[64 * 136];
    __shared__ uint w2u[64];
    const int b = blockIdx.z, i0 = blockIdx.y * 64, j0 = blockIdx.x * 64;
    const int t = threadIdx.x;
    const int sr = t >> 2, c32 = (t & 3) * 32;
    {
        const ushort* rp = rowcol + (size_t)(b * NL + i0 + sr) * 256 + c32;
        const ushort* cp = rowcol + (size_t)(b * NL + j0 + sr) * 256 + 128 + c32;
        #pragma unroll
        for (int q = 0; q < 4; ++q) {
            *(uint4*)&rs[sr * 136 + c32 + q * 8] = *(const uint4*)(rp + q * 8);
            *(uint4*)&cs[sr * 136 + c32 + q * 8] = *(const uint4*)(cp + q * 8);
        }
    }
    if (t < 64) {
        float2 wv = *(const float2*)&w2[2 * t];
        h2v hw = {(_Float16)wv.x, (_Float16)wv.y};
        w2u[t] = __builtin_bit_cast(uint, hw);
    }
    __syncthreads();
    const int lane = t & 63, w = t >> 6;
    const int rg = lane >> 3, cg = lane & 7;
    const int wr = (w >> 1) * 32, wc = (w & 1) * 32;
    float acc[4][4] = {};
    for (int c8 = 0; c8 < 128; c8 += 8) {
        uint wu[4];
        *(uint4*)wu = *(const uint4*)&w2u[c8 >> 1];
        uint ru[4][4], cu[4][4];
        #pragma unroll
        for (int i = 0; i < 4; ++i) {
            uint4 u = *(const uint4*)&rs[(wr + rg + 8 * i) * 136 + c8];
            ru[i][0] = u.x; ru[i][1] = u.y; ru[i][2] = u.z; ru[i][3] = u.w;
            uint4 v = *(const uint4*)&cs[(wc + cg + 8 * i) * 136 + c8];
            cu[i][0] = v.x; cu[i][1] = v.y; cu[i][2] = v.z; cu[i][3] = v.w;
        }
        #pragma unroll
        for (int i = 0; i < 4; ++i)
            #pragma unroll
            for (int j = 0; j < 4; ++j) {
                float a = acc[i][j];
                #pragma unroll
                for (int p = 0; p < 4; ++p)
                    a = fdot2u(addrelu2(ru[i][p], cu[j][p]), wu[p], a);
                acc[i][j] = a;
            }
    }
    const float bb = b2[0];
    #pragma unroll
    for (int i = 0; i < 4; ++i)
        #pragma unroll
        for (int j = 0; j < 4; ++j)
            out[(size_t)(b * NL + i0 + wr + rg + 8 * i) * NL + j0 + wc + cg + 8 * j] =
                acc[i][j] + bb;
}

// ---------------------------------------------------------------------------
extern "C" void kernel_launch(void* const* d_in, const int* in_sizes, int n_in,
                              void* d_out, int out_size, void* d_ws, size_t ws_size,
                              hipStream_t stream)
{
    const float* features  = (const float*)d_in[0];  // [2,768,256]
    const float* in_proj_w = (const float*)d_in[1];  // [768,256]
    const float* in_proj_b = (const float*)d_in[2];  // [768]
    const float* out_w     = (const float*)d_in[3];  // [256,256]
    const float* out_b     = (const float*)d_in[4];  // [256]
    const float* w1        = (const float*)d_in[5];  // [512,128]
    const float* b1        = (const float*)d_in[6];  // [128]
    const float* w2        = (const float*)d_in[7];  // [128,1]
    const float* b2        = (const float*)d_in[8];  // [1]
    float* out = (float*)d_out;                      // [2,768,768]

    ushort* qkvb   = (ushort*)d_ws;                  // [1536,768] bf16
    ushort* attnb  = qkvb + 1179648;                 // [1536,256] bf16
    ushort* WcT    = attnb + 393216;                 // [256,256]  bf16
    float*  bc     = (float*)(WcT + 65536);          // [256] fp32
    ushort* rowcol = (ushort*)(bc + 256);            // [1536,256] fp16

    // 1. qkv projection + combined pairwise weights (641 blocks)
    front_kernel<<<dim3(641), 256, 0, stream>>>(
        features, in_proj_w, in_proj_b, out_w, out_b, w1, b1, qkvb, WcT, bc);

    // 2. flash attention (384 blocks x 128 threads)
    attn_kernel<<<dim3(24, 16), 128, 0, stream>>>(qkvb, attnb);

    // 3. rowcol = attn @ Wc + bc -> fp16 (384 blocks)
    rowcol_kernel<<<dim3(48, 8), 256, 0, stream>>>(attnb, WcT, bc, rowcol);

    // 4. pairwise contact MLP (288 blocks)
    pairwise_kernel<<<dim3(12, 12, 2), 256, 0, stream>>>(rowcol, w2, b2, out);
}

// Round 6
// 60.627 us; speedup vs baseline: 3.0221x; 1.0638x over previous
//
#include <hip/hip_runtime.h>
#include <math.h>

// Problem constants: B=2, L=768, H=256, NH=8, HD=32
#define NL 768

typedef __attribute__((ext_vector_type(8))) short bf16x8;  // 8 bf16 = 4 VGPR
typedef __attribute__((ext_vector_type(4))) float f32x4;
typedef _Float16 h2v __attribute__((ext_vector_type(2)));

static __device__ __forceinline__ ushort f2bf(float f) {
    uint u = __float_as_uint(f);
    u += 0x7fffu + ((u >> 16) & 1u);           // round-to-nearest-even
    return (ushort)(u >> 16);
}
static __device__ __forceinline__ uint pack2(float a, float b) {
    return (uint)f2bf(a) | ((uint)f2bf(b) << 16);
}
// load 8 consecutive fp32 -> bf16x8 fragment (register-only convert)
static __device__ __forceinline__ bf16x8 load8bf(const float* p) {
    float4 a = *(const float4*)p;
    float4 b = *(const float4*)(p + 4);
    uint4 r;
    r.x = pack2(a.x, a.y); r.y = pack2(a.z, a.w);
    r.z = pack2(b.x, b.y); r.w = pack2(b.z, b.w);
    return __builtin_bit_cast(bf16x8, r);
}
// packed fp16: relu(a+b) via v_pk_add_f16 + v_pk_max_f16
static __device__ __forceinline__ uint addrelu2(uint a, uint b) {
    h2v s = __builtin_bit_cast(h2v, a) + __builtin_bit_cast(h2v, b);
    h2v z = {(_Float16)0.f, (_Float16)0.f};
    s = __builtin_elementwise_max(s, z);
    return __builtin_bit_cast(uint, s);
}
// fp32 += dot2(fp16x2, fp16x2) via v_dot2_f32_f16
static __device__ __forceinline__ float fdot2u(uint a, uint b, float c) {
#if __has_builtin(__builtin_amdgcn_fdot2)
    return __builtin_amdgcn_fdot2(__builtin_bit_cast(h2v, a),
                                  __builtin_bit_cast(h2v, b), c, false);
#else
    h2v x = __builtin_bit_cast(h2v, a), y = __builtin_bit_cast(h2v, b);
    return fmaf((float)x[1], (float)y[1], fmaf((float)x[0], (float)y[0], c));
#endif
}

// ---------------------------------------------------------------------------
// front_kernel.
//  blocks [0,576):   per-WAVE 16x32 qkv tiles (no LDS, no barriers).
//    unit u = bid*4+w in [0,2304): m0=(u/24)*16, n0=(u%24)*32.
//    n<512 -> qkvb[m][n] (Q,K); n>=512 -> vt[((b*8+h)*32+d)][seq] (V^T).
//  blocks [576,640): combine_w 32x32 tile (fp32, LDS)
//  block 640:        combine_bias
// ---------------------------------------------------------------------------
__global__ __launch_bounds__(256) void front_kernel(
    const float* __restrict__ features, const float* __restrict__ in_proj_w,
    const float* __restrict__ in_proj_b, const float* __restrict__ out_w,
    const float* __restrict__ out_b, const float* __restrict__ w1,
    const float* __restrict__ b1,
    ushort* __restrict__ qkvb, ushort* __restrict__ vt,
    ushort* __restrict__ WcT, float* __restrict__ bc)
{
    __shared__ float Aw[32][33];
    __shared__ float Bw[32][33];
    const int bid = blockIdx.x;
    const int t = threadIdx.x;
    if (bid < 576) {
        const int lane = t & 63, w = t >> 6;
        const int lg = lane >> 4, lc = lane & 15;
        const int u = bid * 4 + w;
        const int m0 = (u / 24) * 16, n0 = (u % 24) * 32;
        f32x4 acc[2] = {};
        #pragma unroll
        for (int k0 = 0; k0 < 256; k0 += 32) {
            bf16x8 af = load8bf(features + (size_t)(m0 + lc) * 256 + k0 + 8 * lg);
            #pragma unroll
            for (int j = 0; j < 2; ++j) {
                bf16x8 bf = load8bf(in_proj_w + (size_t)(n0 + 16 * j + lc) * 256 + k0 + 8 * lg);
                acc[j] = __builtin_amdgcn_mfma_f32_16x16x32_bf16(af, bf, acc[j], 0, 0, 0);
            }
        }
        const int bb = m0 >= 768;          // batch index (m0 % 768 + 15 < 768)
        const int seq0 = m0 - bb * 768;
        #pragma unroll
        for (int j = 0; j < 2; ++j) {
            int n = n0 + 16 * j + lc;
            float bv = in_proj_b[n];
            if (n < 512) {
                #pragma unroll
                for (int ii = 0; ii < 4; ++ii)
                    qkvb[(size_t)(m0 + 4 * lg + ii) * 768 + n] = f2bf(acc[j][ii] + bv);
            } else {
                int hh = (n - 512) >> 5, dd = (n - 512) & 31;
                ushort* vp = vt + (size_t)((bb * 8 + hh) * 32 + dd) * 768 + seq0 + 4 * lg;
                #pragma unroll
                for (int ii = 0; ii < 4; ++ii)
                    vp[ii] = f2bf(acc[j][ii] + bv);
            }
        }
    } else if (bid < 640) {
        const int u2 = bid - 576;
        const int k0 = (u2 & 7) * 32, c0 = (u2 >> 3) * 32;
        const float* w1x = w1 + (c0 >= 128 ? 256 * 128 : 0);
        const int cc0 = c0 & 127;
        const int tx = t & 15, ty = t >> 4;
        float acc[2][2] = {};
        for (int j0 = 0; j0 < 256; j0 += 32) {
            __syncthreads();
            for (int v = t; v < 32 * 32; v += 256) {
                int r = v >> 5, c = v & 31;
                Aw[r][c] = out_w[(size_t)(j0 + r) * 256 + k0 + c];
                Bw[r][c] = w1x[(size_t)(j0 + r) * 128 + cc0 + c];
            }
            __syncthreads();
            #pragma unroll
            for (int jj = 0; jj < 32; ++jj) {
                float a0 = Aw[jj][ty * 2], a1 = Aw[jj][ty * 2 + 1];
                float b0 = Bw[jj][tx * 2], b1v = Bw[jj][tx * 2 + 1];
                acc[0][0] = fmaf(a0, b0, acc[0][0]);
                acc[0][1] = fmaf(a0, b1v, acc[0][1]);
                acc[1][0] = fmaf(a1, b0, acc[1][0]);
                acc[1][1] = fmaf(a1, b1v, acc[1][1]);
            }
        }
        #pragma unroll
        for (int i = 0; i < 2; ++i)
            #pragma unroll
            for (int j = 0; j < 2; ++j)
                WcT[(size_t)(c0 + tx * 2 + j) * 256 + (k0 + ty * 2 + i)] = f2bf(acc[i][j]);
    } else {
        const float* w1x = w1 + (t >= 128 ? 256 * 128 : 0);
        const int cc = t & 127;
        float a = 0.f;
        #pragma unroll 8
        for (int j = 0; j < 256; ++j)
            a = fmaf(out_b[j], w1x[(size_t)j * 128 + cc], a);
        bc[t] = a + (t < 128 ? b1[cc] : 0.f);
    }
}

// ---------------------------------------------------------------------------
// attn_kernel: grid (48, 16). Block = one 16-row q-tile of one (b,h);
// 4 waves, wave w covers k in [w*192, w*192+192) (split-K flash), partials
// merged via LDS with ONE barrier. K/Q from qkvb, V^T from vt, all global.
// ---------------------------------------------------------------------------
__global__ __launch_bounds__(256) void attn_kernel(
    const ushort* __restrict__ qkvb, const ushort* __restrict__ vt,
    ushort* __restrict__ attnb)
{
    __shared__ __align__(16) ushort Ps[4][16 * 72];
    __shared__ float Ow[4][16][33];
    __shared__ float Lm[4][16];
    __shared__ float Ll[4][16];
    const int qt = blockIdx.x, bh = blockIdx.y, b = bh >> 3, h = bh & 7;
    const int m0 = qt * 16;
    const int t = threadIdx.x, lane = t & 63, w = t >> 6;
    const int lg = lane >> 4, lc = lane & 15;
    const float SC = 0.17677669529663687f;   // 1/sqrt(32)
    const ushort* qbase = qkvb + (size_t)(b * NL) * 768;
    const ushort* vbase = vt + (size_t)((b * 8 + h) * 32) * 768;
    ushort* Pw = Ps[w];

    bf16x8 qa = *(const bf16x8*)(qbase + (size_t)(m0 + lc) * 768 + h * 32 + 8 * lg);

    f32x4 o0 = {}, o1 = {};
    float mr[4] = {-1e30f, -1e30f, -1e30f, -1e30f};
    float lr[4] = {0.f, 0.f, 0.f, 0.f};

    for (int kt = 0; kt < 3; ++kt) {
        const int k0 = w * 192 + kt * 64;
        f32x4 s[4];
        #pragma unroll
        for (int t4 = 0; t4 < 4; ++t4) {
            bf16x8 kb = *(const bf16x8*)(qbase + (size_t)(k0 + 16 * t4 + lc) * 768
                                         + 256 + h * 32 + 8 * lg);
            f32x4 z = {};
            s[t4] = __builtin_amdgcn_mfma_f32_16x16x32_bf16(qa, kb, z, 0, 0, 0);
        }
        #pragma unroll
        for (int i = 0; i < 4; ++i) {
            float mx = fmaxf(fmaxf(s[0][i], s[1][i]), fmaxf(s[2][i], s[3][i]));
            #pragma unroll
            for (int off = 1; off < 16; off <<= 1) mx = fmaxf(mx, __shfl_xor(mx, off));
            float mnew = fmaxf(mr[i], mx * SC);
            float resc = __expf(mr[i] - mnew);
            float tsum = 0.f;
            #pragma unroll
            for (int t4 = 0; t4 < 4; ++t4) {
                float p = __expf(s[t4][i] * SC - mnew);
                tsum += p;
                Pw[(4 * lg + i) * 72 + 16 * t4 + lc] = f2bf(p);
            }
            #pragma unroll
            for (int off = 1; off < 16; off <<= 1) tsum += __shfl_xor(tsum, off);
            mr[i] = mnew;
            lr[i] = lr[i] * resc + tsum;
            o0[i] *= resc;
            o1[i] *= resc;
        }
        bf16x8 pa0 = *(const bf16x8*)&Pw[lc * 72 + 8 * lg];
        bf16x8 pa1 = *(const bf16x8*)&Pw[lc * 72 + 32 + 8 * lg];
        bf16x8 v00 = *(const bf16x8*)(vbase + (size_t)lc * 768 + k0 + 8 * lg);
        bf16x8 v01 = *(const bf16x8*)(vbase + (size_t)lc * 768 + k0 + 32 + 8 * lg);
        bf16x8 v10 = *(const bf16x8*)(vbase + (size_t)(16 + lc) * 768 + k0 + 8 * lg);
        bf16x8 v11 = *(const bf16x8*)(vbase + (size_t)(16 + lc) * 768 + k0 + 32 + 8 * lg);
        o0 = __builtin_amdgcn_mfma_f32_16x16x32_bf16(pa0, v00, o0, 0, 0, 0);
        o0 = __builtin_amdgcn_mfma_f32_16x16x32_bf16(pa1, v01, o0, 0, 0, 0);
        o1 = __builtin_amdgcn_mfma_f32_16x16x32_bf16(pa0, v10, o1, 0, 0, 0);
        o1 = __builtin_amdgcn_mfma_f32_16x16x32_bf16(pa1, v11, o1, 0, 0, 0);
    }
    // publish partials
    #pragma unroll
    for (int i = 0; i < 4; ++i) {
        Ow[w][4 * lg + i][lc] = o0[i];
        Ow[w][4 * lg + i][16 + lc] = o1[i];
    }
    if (lc == 0) {
        #pragma unroll
        for (int i = 0; i < 4; ++i) {
            Lm[w][4 * lg + i] = mr[i];
            Ll[w][4 * lg + i] = lr[i];
        }
    }
    __syncthreads();
    if (w == 0) {
        #pragma unroll
        for (int i = 0; i < 4; ++i) {
            int row = 4 * lg + i;
            float M = fmaxf(fmaxf(Lm[0][row], Lm[1][row]), fmaxf(Lm[2][row], Lm[3][row]));
            float L = 0.f, a0 = 0.f, a1 = 0.f;
            #pragma unroll
            for (int k = 0; k < 4; ++k) {
                float e = __expf(Lm[k][row] - M);
                L += Ll[k][row] * e;
                a0 += Ow[k][row][lc] * e;
                a1 += Ow[k][row][16 + lc] * e;
            }
            float inv = 1.f / L;
            size_t orow = (size_t)(b * NL + m0 + row);
            attnb[orow * 256 + h * 32 + lc] = f2bf(a0 * inv);
            attnb[orow * 256 + h * 32 + 16 + lc] = f2bf(a1 * inv);
        }
    }
}

// ---------------------------------------------------------------------------
// rowcol_kernel: per-wave 16x16 tile, K=256, no LDS. 384 blocks.
// rowcol[m][n] = attnb[m,:]·WcT[n,:] + bc[n]  -> fp16
// ---------------------------------------------------------------------------
__global__ __launch_bounds__(256) void rowcol_kernel(
    const ushort* __restrict__ attnb, const ushort* __restrict__ WcT,
    const float* __restrict__ bc, ushort* __restrict__ rowcol)
{
    const int t = threadIdx.x, lane = t & 63, w = t >> 6;
    const int lg = lane >> 4, lc = lane & 15;
    const int u = blockIdx.x * 4 + w;          // [0,1536)
    const int m0 = (u >> 4) * 16, n0 = (u & 15) * 16;
    f32x4 acc = {};
    #pragma unroll
    for (int k0 = 0; k0 < 256; k0 += 32) {
        bf16x8 a = *(const bf16x8*)(attnb + (size_t)(m0 + lc) * 256 + k0 + 8 * lg);
        bf16x8 bfr = *(const bf16x8*)(WcT + (size_t)(n0 + lc) * 256 + k0 + 8 * lg);
        acc = __builtin_amdgcn_mfma_f32_16x16x32_bf16(a, bfr, acc, 0, 0, 0);
    }
    const int n = n0 + lc;
    const float bv = bc[n];
    #pragma unroll
    for (int ii = 0; ii < 4; ++ii)
        ((_Float16*)rowcol)[(size_t)(m0 + 4 * lg + ii) * 256 + n] = (_Float16)(acc[ii] + bv);
}

// ---------------------------------------------------------------------------
// pairwise_kernel: grid (12, 24, 2); block tile 32(i) x 64(j), 4 waves 2x2,
// per-lane 2x4 outputs; fp16 addrelu+dot2; broadcast-friendly LDS.
// ---------------------------------------------------------------------------
__global__ __launch_bounds__(256) void pairwise_kernel(
    const ushort* __restrict__ rowcol, const float* __restrict__ w2,
    const float* __restrict__ b2, float* __restrict__ out)
{
    __shared__ __align__(16) ushort rs[32 * 136];
    __shared__ __align__(16) ushort cs[64 * 136];
    __shared__ uint w2u[64];
    const int b = blockIdx.z, i0 = blockIdx.y * 32, j0 = blockIdx.x * 64;
    const int t = threadIdx.x;
    #pragma unroll
    for (int v = t; v < 512; v += 256) {
        int r = v >> 4, q = v & 15;
        *(uint4*)&rs[r * 136 + q * 8] =
            *(const uint4*)(rowcol + (size_t)(b * NL + i0 + r) * 256 + q * 8);
    }
    #pragma unroll
    for (int v = t; v < 1024; v += 256) {
        int r = v >> 4, q = v & 15;
        *(uint4*)&cs[r * 136 + q * 8] =
            *(const uint4*)(rowcol + (size_t)(b * NL + j0 + r) * 256 + 128 + q * 8);
    }
    if (t < 64) {
        float2 wv = *(const float2*)&w2[2 * t];
        h2v hw = {(_Float16)wv.x, (_Float16)wv.y};
        w2u[t] = __builtin_bit_cast(uint, hw);
    }
    __syncthreads();
    const int lane = t & 63, w = t >> 6;
    const int rg = lane >> 3, cg = lane & 7;
    const int wy = w >> 1, wx = w & 1;
    float acc[2][4] = {};
    for (int c8 = 0; c8 < 128; c8 += 8) {
        uint wu[4];
        *(uint4*)wu = *(const uint4*)&w2u[c8 >> 1];
        uint ru[2][4], cu[4][4];
        #pragma unroll
        for (int i = 0; i < 2; ++i)
            *(uint4*)ru[i] = *(const uint4*)&rs[(16 * wy + rg + 8 * i) * 136 + c8];
        #pragma unroll
        for (int j = 0; j < 4; ++j)
            *(uint4*)cu[j] = *(const uint4*)&cs[(32 * wx + cg + 8 * j) * 136 + c8];
        #pragma unroll
        for (int i = 0; i < 2; ++i)
            #pragma unroll
            for (int j = 0; j < 4; ++j) {
                float a = acc[i][j];
                #pragma unroll
                for (int p = 0; p < 4; ++p)
                    a = fdot2u(addrelu2(ru[i][p], cu[j][p]), wu[p], a);
                acc[i][j] = a;
            }
    }
    const float bb = b2[0];
    #pragma unroll
    for (int i = 0; i < 2; ++i)
        #pragma unroll
        for (int j = 0; j < 4; ++j)
            out[(size_t)(b * NL + i0 + 16 * wy + rg + 8 * i) * NL
                + j0 + 32 * wx + cg + 8 * j] = acc[i][j] + bb;
}

// ---------------------------------------------------------------------------
extern "C" void kernel_launch(void* const* d_in, const int* in_sizes, int n_in,
                              void* d_out, int out_size, void* d_ws, size_t ws_size,
                              hipStream_t stream)
{
    const float* features  = (const float*)d_in[0];  // [2,768,256]
    const float* in_proj_w = (const float*)d_in[1];  // [768,256]
    const float* in_proj_b = (const float*)d_in[2];  // [768]
    const float* out_w     = (const float*)d_in[3];  // [256,256]
    const float* out_b     = (const float*)d_in[4];  // [256]
    const float* w1        = (const float*)d_in[5];  // [512,128]
    const float* b1        = (const float*)d_in[6];  // [128]
    const float* w2        = (const float*)d_in[7];  // [128,1]
    const float* b2        = (const float*)d_in[8];  // [1]
    float* out = (float*)d_out;                      // [2,768,768]

    ushort* qkvb   = (ushort*)d_ws;                  // [1536,768] bf16 (Q,K cols)
    ushort* vt     = qkvb + 1179648;                 // [512,768]  bf16 V^T
    ushort* attnb  = vt + 393216;                    // [1536,256] bf16
    ushort* WcT    = attnb + 393216;                 // [256,256]  bf16
    float*  bc     = (float*)(WcT + 65536);          // [256] fp32
    ushort* rowcol = (ushort*)(bc + 256);            // [1536,256] fp16

    // 1. qkv projection (per-wave tiles, V transposed) + combined weights
    front_kernel<<<dim3(641), 256, 0, stream>>>(
        features, in_proj_w, in_proj_b, out_w, out_b, w1, b1, qkvb, vt, WcT, bc);

    // 2. split-K flash attention (768 blocks x 4 waves)
    attn_kernel<<<dim3(48, 16), 256, 0, stream>>>(qkvb, vt, attnb);

    // 3. rowcol = attn @ Wc + bc -> fp16 (per-wave 16x16, 384 blocks)
    rowcol_kernel<<<dim3(384), 256, 0, stream>>>(attnb, WcT, bc, rowcol);

    // 4. pairwise contact MLP (576 blocks)
    pairwise_kernel<<<dim3(12, 24, 2), 256, 0, stream>>>(rowcol, w2, b2, out);
}

// Round 7
// 59.379 us; speedup vs baseline: 3.0856x; 1.0210x over previous
//
#include <hip/hip_runtime.h>
#include <math.h>

// Problem constants: B=2, L=768, H=256, NH=8, HD=32
#define NL 768

typedef __attribute__((ext_vector_type(8))) short bf16x8;  // 8 bf16 = 4 VGPR
typedef __attribute__((ext_vector_type(4))) float f32x4;
typedef _Float16 h2v __attribute__((ext_vector_type(2)));

static __device__ __forceinline__ ushort f2bf(float f) {
    uint u = __float_as_uint(f);
    u += 0x7fffu + ((u >> 16) & 1u);           // round-to-nearest-even
    return (ushort)(u >> 16);
}
static __device__ __forceinline__ uint pack2(float a, float b) {
    return (uint)f2bf(a) | ((uint)f2bf(b) << 16);
}
// load 8 consecutive fp32 -> bf16x8 fragment (register-only convert)
static __device__ __forceinline__ bf16x8 load8bf(const float* p) {
    float4 a = *(const float4*)p;
    float4 b = *(const float4*)(p + 4);
    uint4 r;
    r.x = pack2(a.x, a.y); r.y = pack2(a.z, a.w);
    r.z = pack2(b.x, b.y); r.w = pack2(b.z, b.w);
    return __builtin_bit_cast(bf16x8, r);
}
// packed fp16: relu(a+b) via v_pk_add_f16 + v_pk_max_f16
static __device__ __forceinline__ uint addrelu2(uint a, uint b) {
    h2v s = __builtin_bit_cast(h2v, a) + __builtin_bit_cast(h2v, b);
    h2v z = {(_Float16)0.f, (_Float16)0.f};
    s = __builtin_elementwise_max(s, z);
    return __builtin_bit_cast(uint, s);
}
// fp32 += dot2(fp16x2, fp16x2) via v_dot2_f32_f16
static __device__ __forceinline__ float fdot2u(uint a, uint b, float c) {
#if __has_builtin(__builtin_amdgcn_fdot2)
    return __builtin_amdgcn_fdot2(__builtin_bit_cast(h2v, a),
                                  __builtin_bit_cast(h2v, b), c, false);
#else
    h2v x = __builtin_bit_cast(h2v, a), y = __builtin_bit_cast(h2v, b);
    return fmaf((float)x[1], (float)y[1], fmaf((float)x[0], (float)y[0], c));
#endif
}
static __device__ __forceinline__ float fexp2(float x) {
#if __has_builtin(__builtin_amdgcn_exp2f)
    return __builtin_amdgcn_exp2f(x);
#else
    return exp2f(x);
#endif
}

// 1/sqrt(32) * log2(e): folded into Q at write time so attn uses exp2 directly
#define QSC 0.25503487f

// ---------------------------------------------------------------------------
// front_kernel.
//  blocks [0,576):   per-WAVE 16x32 qkv tiles (no LDS, no barriers).
//    n<256 -> Q (pre-scaled by QSC) -> qkvb[m][n]
//    256<=n<512 -> K -> qkvb[m][n]
//    n>=512 -> V -> vtp[(b,h,d)][seq], k-SLOT-PERMUTED within each 32-chunk:
//       pos(k) = (k & ~31) + 8*((k>>2)&3) + 4*((k>>4)&1) + (k&3)
//       so attn's PV B-fragment slot order matches P's natural register order.
//  blocks [576,640): combine_w 32x32 tile; block 640: combine_bias.
// ---------------------------------------------------------------------------
__global__ __launch_bounds__(256) void front_kernel(
    const float* __restrict__ features, const float* __restrict__ in_proj_w,
    const float* __restrict__ in_proj_b, const float* __restrict__ out_w,
    const float* __restrict__ out_b, const float* __restrict__ w1,
    const float* __restrict__ b1,
    ushort* __restrict__ qkvb, ushort* __restrict__ vtp,
    ushort* __restrict__ WcT, float* __restrict__ bc)
{
    __shared__ float Aw[32][33];
    __shared__ float Bw[32][33];
    const int bid = blockIdx.x;
    const int t = threadIdx.x;
    if (bid < 576) {
        const int lane = t & 63, w = t >> 6;
        const int lg = lane >> 4, lc = lane & 15;
        const int u = bid * 4 + w;
        const int m0 = (u / 24) * 16, n0 = (u % 24) * 32;
        f32x4 acc[2] = {};
        #pragma unroll
        for (int k0 = 0; k0 < 256; k0 += 32) {
            bf16x8 af = load8bf(features + (size_t)(m0 + lc) * 256 + k0 + 8 * lg);
            #pragma unroll
            for (int j = 0; j < 2; ++j) {
                bf16x8 bf = load8bf(in_proj_w + (size_t)(n0 + 16 * j + lc) * 256 + k0 + 8 * lg);
                acc[j] = __builtin_amdgcn_mfma_f32_16x16x32_bf16(af, bf, acc[j], 0, 0, 0);
            }
        }
        const int bb = m0 >= 768;          // batch index (m0 is 16-aligned)
        const int seq0 = m0 - bb * 768;
        #pragma unroll
        for (int j = 0; j < 2; ++j) {
            int n = n0 + 16 * j + lc;
            float bv = in_proj_b[n];
            float sc = (n0 + 16 * j) < 256 ? QSC : 1.0f;   // wave-uniform per j
            if (n < 512) {
                #pragma unroll
                for (int ii = 0; ii < 4; ++ii)
                    qkvb[(size_t)(m0 + 4 * lg + ii) * 768 + n] =
                        f2bf((acc[j][ii] + bv) * sc);
            } else {
                int hh = (n - 512) >> 5, dd = (n - 512) & 31;
                int seqb = seq0 + 4 * lg;              // 4-aligned
                int pos = (seqb & ~31) + 8 * ((seqb >> 2) & 3) + 4 * ((seqb >> 4) & 1);
                ushort* vp = vtp + (size_t)((bb * 8 + hh) * 32 + dd) * 768 + pos;
                uint lo = pack2(acc[j][0] + bv, acc[j][1] + bv);
                uint hi = pack2(acc[j][2] + bv, acc[j][3] + bv);
                *(uint2*)vp = make_uint2(lo, hi);
            }
        }
    } else if (bid < 640) {
        const int u2 = bid - 576;
        const int k0 = (u2 & 7) * 32, c0 = (u2 >> 3) * 32;
        const float* w1x = w1 + (c0 >= 128 ? 256 * 128 : 0);
        const int cc0 = c0 & 127;
        const int tx = t & 15, ty = t >> 4;
        float acc[2][2] = {};
        for (int j0 = 0; j0 < 256; j0 += 32) {
            __syncthreads();
            for (int v = t; v < 32 * 32; v += 256) {
                int r = v >> 5, c = v & 31;
                Aw[r][c] = out_w[(size_t)(j0 + r) * 256 + k0 + c];
                Bw[r][c] = w1x[(size_t)(j0 + r) * 128 + cc0 + c];
            }
            __syncthreads();
            #pragma unroll
            for (int jj = 0; jj < 32; ++jj) {
                float a0 = Aw[jj][ty * 2], a1 = Aw[jj][ty * 2 + 1];
                float b0 = Bw[jj][tx * 2], b1v = Bw[jj][tx * 2 + 1];
                acc[0][0] = fmaf(a0, b0, acc[0][0]);
                acc[0][1] = fmaf(a0, b1v, acc[0][1]);
                acc[1][0] = fmaf(a1, b0, acc[1][0]);
                acc[1][1] = fmaf(a1, b1v, acc[1][1]);
            }
        }
        #pragma unroll
        for (int i = 0; i < 2; ++i)
            #pragma unroll
            for (int j = 0; j < 2; ++j)
                WcT[(size_t)(c0 + tx * 2 + j) * 256 + (k0 + ty * 2 + i)] = f2bf(acc[i][j]);
    } else {
        const float* w1x = w1 + (t >= 128 ? 256 * 128 : 0);
        const int cc = t & 127;
        float a = 0.f;
        #pragma unroll 8
        for (int j = 0; j < 256; ++j)
            a = fmaf(out_b[j], w1x[(size_t)j * 128 + cc], a);
        bc[t] = a + (t < 128 ? b1[cc] : 0.f);
    }
}

// ---------------------------------------------------------------------------
// attn_kernel: grid (48, 16). Block = one 16-row q-tile of one (b,h);
// 4 waves split K (192 each). Swapped QK^T (mfma(K,Q)) + no-max softmax
// (p = 2^s, Q pre-scaled) + slot-permuted V so P feeds PV directly.
// Inner loop: NO LDS, NO shfl, NO barriers. One barrier for split-K merge.
// ---------------------------------------------------------------------------
__global__ __launch_bounds__(256) void attn_kernel(
    const ushort* __restrict__ qkvb, const ushort* __restrict__ vtp,
    ushort* __restrict__ attnb)
{
    __shared__ float Ow[4][16][33];
    __shared__ float Lw[4][16];
    const int qt = blockIdx.x, bh = blockIdx.y, b = bh >> 3, h = bh & 7;
    const int m0 = qt * 16;
    const int t = threadIdx.x, lane = t & 63, w = t >> 6;
    const int lg = lane >> 4, lc = lane & 15;
    const ushort* qbase = qkvb + (size_t)(b * NL) * 768;
    const ushort* vbase = vtp + (size_t)((b * 8 + h) * 32) * 768;

    // Q fragment (B-operand): lane lc = q-row m0+lc, slots d = 8*lg..+7
    bf16x8 qa = *(const bf16x8*)(qbase + (size_t)(m0 + lc) * 768 + h * 32 + 8 * lg);

    f32x4 o0 = {}, o1 = {};
    float lsum = 0.f;

    for (int kt = 0; kt < 3; ++kt) {
        const int k0 = w * 192 + kt * 64;
        f32x4 s[4];
        #pragma unroll
        for (int t4 = 0; t4 < 4; ++t4) {
            // K fragment (A-operand): lane lc = k-row k0+16*t4+lc
            bf16x8 kb = *(const bf16x8*)(qbase + (size_t)(k0 + 16 * t4 + lc) * 768
                                         + 256 + h * 32 + 8 * lg);
            f32x4 z = {};
            // S[k_local=4*lg+i][q=lc] per t4 block
            s[t4] = __builtin_amdgcn_mfma_f32_16x16x32_bf16(kb, qa, z, 0, 0, 0);
        }
        uint pk[4][2];
        #pragma unroll
        for (int t4 = 0; t4 < 4; ++t4) {
            float p0 = fexp2(s[t4][0]);
            float p1 = fexp2(s[t4][1]);
            float p2 = fexp2(s[t4][2]);
            float p3 = fexp2(s[t4][3]);
            lsum += (p0 + p1) + (p2 + p3);
            pk[t4][0] = pack2(p0, p1);
            pk[t4][1] = pack2(p2, p3);
        }
        // PV: P's register order IS the A-frag slot order (V is slot-permuted)
        #pragma unroll
        for (int c = 0; c < 2; ++c) {
            uint4 au;
            au.x = pk[2 * c][0];     au.y = pk[2 * c][1];
            au.z = pk[2 * c + 1][0]; au.w = pk[2 * c + 1][1];
            bf16x8 pa = __builtin_bit_cast(bf16x8, au);
            bf16x8 v0 = *(const bf16x8*)(vbase + (size_t)lc * 768 + k0 + 32 * c + 8 * lg);
            bf16x8 v1 = *(const bf16x8*)(vbase + (size_t)(16 + lc) * 768 + k0 + 32 * c + 8 * lg);
            o0 = __builtin_amdgcn_mfma_f32_16x16x32_bf16(pa, v0, o0, 0, 0, 0);
            o1 = __builtin_amdgcn_mfma_f32_16x16x32_bf16(pa, v1, o1, 0, 0, 0);
        }
    }
    // row-sum of l across the 4 lg groups (same q = lc)
    lsum += __shfl_xor(lsum, 16);
    lsum += __shfl_xor(lsum, 32);
    // publish partials: O lane (lg,lc): q = 4*lg+i, d = lc / 16+lc
    #pragma unroll
    for (int i = 0; i < 4; ++i) {
        Ow[w][4 * lg + i][lc] = o0[i];
        Ow[w][4 * lg + i][16 + lc] = o1[i];
    }
    if (lg == 0) Lw[w][lc] = lsum;
    __syncthreads();
    // merge: wave w owns q rows 4w..4w+3; lane (lg,lc) -> (q=4w+lg, d=lc,16+lc)
    {
        const int q = 4 * w + lg;
        float l = (Lw[0][q] + Lw[1][q]) + (Lw[2][q] + Lw[3][q]);
        float inv = 1.f / l;
        float a0 = (Ow[0][q][lc] + Ow[1][q][lc]) + (Ow[2][q][lc] + Ow[3][q][lc]);
        float a1 = (Ow[0][q][16 + lc] + Ow[1][q][16 + lc])
                 + (Ow[2][q][16 + lc] + Ow[3][q][16 + lc]);
        size_t orow = (size_t)(b * NL + m0 + q);
        attnb[orow * 256 + h * 32 + lc] = f2bf(a0 * inv);
        attnb[orow * 256 + h * 32 + 16 + lc] = f2bf(a1 * inv);
    }
}

// ---------------------------------------------------------------------------
// rowcol_kernel: per-wave 16x16 tile, K=256, no LDS. 384 blocks.
// rowcol[m][n] = attnb[m,:]·WcT[n,:] + bc[n]  -> fp16
// ---------------------------------------------------------------------------
__global__ __launch_bounds__(256) void rowcol_kernel(
    const ushort* __restrict__ attnb, const ushort* __restrict__ WcT,
    const float* __restrict__ bc, ushort* __restrict__ rowcol)
{
    const int t = threadIdx.x, lane = t & 63, w = t >> 6;
    const int lg = lane >> 4, lc = lane & 15;
    const int u = blockIdx.x * 4 + w;          // [0,1536)
    const int m0 = (u >> 4) * 16, n0 = (u & 15) * 16;
    f32x4 acc = {};
    #pragma unroll
    for (int k0 = 0; k0 < 256; k0 += 32) {
        bf16x8 a = *(const bf16x8*)(attnb + (size_t)(m0 + lc) * 256 + k0 + 8 * lg);
        bf16x8 bfr = *(const bf16x8*)(WcT + (size_t)(n0 + lc) * 256 + k0 + 8 * lg);
        acc = __builtin_amdgcn_mfma_f32_16x16x32_bf16(a, bfr, acc, 0, 0, 0);
    }
    const int n = n0 + lc;
    const float bv = bc[n];
    #pragma unroll
    for (int ii = 0; ii < 4; ++ii)
        ((_Float16*)rowcol)[(size_t)(m0 + 4 * lg + ii) * 256 + n] = (_Float16)(acc[ii] + bv);
}

// ---------------------------------------------------------------------------
// pairwise_kernel: grid (12, 24, 2); block tile 32(i) x 64(j), 4 waves 2x2,
// per-lane 2x4 outputs; fp16 addrelu+dot2; broadcast-friendly LDS.
// ---------------------------------------------------------------------------
__global__ __launch_bounds__(256) void pairwise_kernel(
    const ushort* __restrict__ rowcol, const float* __restrict__ w2,
    const float* __restrict__ b2, float* __restrict__ out)
{
    __shared__ __align__(16) ushort rs[32 * 136];
    __shared__ __align__(16) ushort cs[64 * 136];
    __shared__ uint w2u[64];
    const int b = blockIdx.z, i0 = blockIdx.y * 32, j0 = blockIdx.x * 64;
    const int t = threadIdx.x;
    #pragma unroll
    for (int v = t; v < 512; v += 256) {
        int r = v >> 4, q = v & 15;
        *(uint4*)&rs[r * 136 + q * 8] =
            *(const uint4*)(rowcol + (size_t)(b * NL + i0 + r) * 256 + q * 8);
    }
    #pragma unroll
    for (int v = t; v < 1024; v += 256) {
        int r = v >> 4, q = v & 15;
        *(uint4*)&cs[r * 136 + q * 8] =
            *(const uint4*)(rowcol + (size_t)(b * NL + j0 + r) * 256 + 128 + q * 8);
    }
    if (t < 64) {
        float2 wv = *(const float2*)&w2[2 * t];
        h2v hw = {(_Float16)wv.x, (_Float16)wv.y};
        w2u[t] = __builtin_bit_cast(uint, hw);
    }
    __syncthreads();
    const int lane = t & 63, w = t >> 6;
    const int rg = lane >> 3, cg = lane & 7;
    const int wy = w >> 1, wx = w & 1;
    float acc[2][4] = {};
    for (int c8 = 0; c8 < 128; c8 += 8) {
        uint wu[4];
        *(uint4*)wu = *(const uint4*)&w2u[c8 >> 1];
        uint ru[2][4], cu[4][4];
        #pragma unroll
        for (int i = 0; i < 2; ++i)
            *(uint4*)ru[i] = *(const uint4*)&rs[(16 * wy + rg + 8 * i) * 136 + c8];
        #pragma unroll
        for (int j = 0; j < 4; ++j)
            *(uint4*)cu[j] = *(const uint4*)&cs[(32 * wx + cg + 8 * j) * 136 + c8];
        #pragma unroll
        for (int i = 0; i < 2; ++i)
            #pragma unroll
            for (int j = 0; j < 4; ++j) {
                float a = acc[i][j];
                #pragma unroll
                for (int p = 0; p < 4; ++p)
                    a = fdot2u(addrelu2(ru[i][p], cu[j][p]), wu[p], a);
                acc[i][j] = a;
            }
    }
    const float bb = b2[0];
    #pragma unroll
    for (int i = 0; i < 2; ++i)
        #pragma unroll
        for (int j = 0; j < 4; ++j)
            out[(size_t)(b * NL + i0 + 16 * wy + rg + 8 * i) * NL
                + j0 + 32 * wx + cg + 8 * j] = acc[i][j] + bb;
}

// ---------------------------------------------------------------------------
extern "C" void kernel_launch(void* const* d_in, const int* in_sizes, int n_in,
                              void* d_out, int out_size, void* d_ws, size_t ws_size,
                              hipStream_t stream)
{
    const float* features  = (const float*)d_in[0];  // [2,768,256]
    const float* in_proj_w = (const float*)d_in[1];  // [768,256]
    const float* in_proj_b = (const float*)d_in[2];  // [768]
    const float* out_w     = (const float*)d_in[3];  // [256,256]
    const float* out_b     = (const float*)d_in[4];  // [256]
    const float* w1        = (const float*)d_in[5];  // [512,128]
    const float* b1        = (const float*)d_in[6];  // [128]
    const float* w2        = (const float*)d_in[7];  // [128,1]
    const float* b2        = (const float*)d_in[8];  // [1]
    float* out = (float*)d_out;                      // [2,768,768]

    ushort* qkvb   = (ushort*)d_ws;                  // [1536,768] bf16 (Q scaled, K)
    ushort* vtp    = qkvb + 1179648;                 // [512,768]  bf16 V^T, slot-permuted
    ushort* attnb  = vtp + 393216;                   // [1536,256] bf16
    ushort* WcT    = attnb + 393216;                 // [256,256]  bf16
    float*  bc     = (float*)(WcT + 65536);          // [256] fp32
    ushort* rowcol = (ushort*)(bc + 256);            // [1536,256] fp16

    // 1. qkv projection (per-wave tiles; Q pre-scaled, V slot-permuted) + weights
    front_kernel<<<dim3(641), 256, 0, stream>>>(
        features, in_proj_w, in_proj_b, out_w, out_b, w1, b1, qkvb, vtp, WcT, bc);

    // 2. split-K flash attention, barrier-free inner loop (768 blocks)
    attn_kernel<<<dim3(48, 16), 256, 0, stream>>>(qkvb, vtp, attnb);

    // 3. rowcol = attn @ Wc + bc -> fp16 (per-wave 16x16, 384 blocks)
    rowcol_kernel<<<dim3(384), 256, 0, stream>>>(attnb, WcT, bc, rowcol);

    // 4. pairwise contact MLP (576 blocks)
    pairwise_kernel<<<dim3(12, 24, 2), 256, 0, stream>>>(rowcol, w2, b2, out);
}